// Round 13
// baseline (4330.138 us; speedup 1.0000x reference)
//
#include <hip/hip_runtime.h>

// Problem constants
#define Tt 256

// ws layout in unsigned shorts (fp16 bit patterns / ints for flags):
//  flags : ints [0..256) arrival flags (4B packed)      [first 1KB of 32KB region]
//  h0 [4 planes mod-4][64 g][128 row][8] fp16 frag-major  [512 KB]  (g = col>>3)
//  h1 [2 planes mod-2][64 g][128 row][8]                  [256 KB]
//  w0lo [64 cg][104 kg][32 n][8]  fp16, lo=(w-fp16(w))*1024, block-private frag-lane order
//  w1lo [64 cg][128 kg][32 n][8]
// total = 4,210,688 shorts = 8,421,376 B (< 8,650,752 proven R1-R3 budget)
#define FLAGS_SHORTS 16384
#define H0OFF  16384
#define HPAR   (64*128*8)            // u16 per plane = 65536
#define H1OFF  (H0OFF + 4*HPAR)
#define W0LOFF (H1OFF + 2*HPAR)
#define W1LOFF (W0LOFF + 64*104*32*8)

typedef _Float16 h8 __attribute__((ext_vector_type(8)));
typedef float    f4 __attribute__((ext_vector_type(4)));
typedef unsigned long long ull;
typedef unsigned short u16;

#define MFMA __builtin_amdgcn_mfma_f32_16x16x32_f16
#define LOSC (1.0f/1024.0f)

__device__ inline u16 h_bits(float f){ union{_Float16 h; u16 s;} u; u.h=(_Float16)f; return u.s; }
__device__ inline float bits_f(u16 s){ union{u16 s2; _Float16 h;} u; u.s2=s; return (float)u.h; }
__device__ inline float sigm(float x){ return 1.f/(1.f+expf(-x)); }

// Coherent 16B A-fragment load: two relaxed agent-scope 8B atomic loads (IF$-served, proven R2..R11).
__device__ inline h8 ldH(const u16* p){
    union{ ull u[2]; h8 v; } t;
    t.u[0]=__hip_atomic_load((const ull*)p,    __ATOMIC_RELAXED, __HIP_MEMORY_SCOPE_AGENT);
    t.u[1]=__hip_atomic_load((const ull*)(p+4),__ATOMIC_RELAXED, __HIP_MEMORY_SCOPE_AGENT);
    return t.v;
}

// ---------------- pre-pack W lo-planes (fp16, x1024), [cg][kg][n 0..32)[8] — R9 verbatim ----------------
__global__ __launch_bounds__(256) void prepack(const float* __restrict__ W0,
                                               const float* __restrict__ W1,
                                               u16* __restrict__ ws) {
    int idx = blockIdx.x * 256 + threadIdx.x;
    const int NW0 = 64 * 104 * 32;
    if (idx < NW0) {
        int cg  = idx / (104 * 32);
        int rem = idx - cg * (104 * 32);
        int kg = rem >> 5, n = rem & 31;
        int col = ((n >> 3) << 9) + (cg << 3) + (n & 7);
        u16 t[8];
#pragma unroll
        for (int j = 0; j < 8; j++) {
            int k = kg * 8 + j;
            float w = 0.f;
            if (k < 300) w = W0[k * 2048 + col];
            else if (k >= 320) w = W0[(k - 20) * 2048 + col];
            _Float16 wh = (_Float16)w;
            t[j] = h_bits((w - (float)wh) * 1024.0f);
        }
#pragma unroll
        for (int j = 0; j < 8; j++) ws[W0LOFF + (size_t)idx * 8 + j] = t[j];
    } else {
        int i2 = idx - NW0;
        if (i2 < 64 * 128 * 32) {
            int cg  = i2 >> 12;
            int rem = i2 & 4095;
            int kg = rem >> 5, n = rem & 31;
            int col = ((n >> 3) << 9) + (cg << 3) + (n & 7);
            u16 t[8];
#pragma unroll
            for (int j = 0; j < 8; j++) {
                float w = W1[(kg * 8 + j) * 2048 + col];
                _Float16 wh = (_Float16)w;
                t[j] = h_bits((w - (float)wh) * 1024.0f);
            }
#pragma unroll
            for (int j = 0; j < 8; j++) ws[W1LOFF + (size_t)i2 * 8 + j] = t[j];
        }
    }
}

// arrive: drain write-through stores, block-sync, publish own flag (R11 verbatim).
__device__ inline void barrier_arrive(int* __restrict__ flags, int tid, int bid, int target) {
    __builtin_amdgcn_s_waitcnt(0);
    __syncthreads();
    if (tid == 0)
        __hip_atomic_store(flags + bid, target, __ATOMIC_RELAXED, __HIP_MEMORY_SCOPE_AGENT);
}
// Split wait (R13): same-batch-half only. Lane l covers cg=l: one 8B load yields the
// (lyr0,lyr1) flag pair of that cg. Wait until lyr0 flags >= t0 AND lyr1 flags >= t1.
// Only wave 0 polls (R11-proven de-contended form); waves 1..3 park at __syncthreads.
__device__ inline void wait_split(int* __restrict__ flags, int tid, int bq, int t0, int t1) {
    if (tid < 64) {
        const ull* fp = (const ull*)(flags + (bq << 7)) + tid;
        for (;;) {
            ull v = __hip_atomic_load(fp, __ATOMIC_RELAXED, __HIP_MEMORY_SCOPE_AGENT);
            bool ok = ((int)(unsigned)v >= t0) && ((int)(unsigned)(v >> 32) >= t1);
            if (__ballot(ok) == ~0ull) break;
            __builtin_amdgcn_s_sleep(1);
        }
    }
    __syncthreads();
}

struct X4 { f4 h0, l0, h1, l1; };

// ---------------- persistent cooperative LSTM kernel ----------------
// grid 256 x 256 (1 block/CU): bid = inner*2 + lyr; inner = bq*64 + cg.  R11 structure;
// R13: h0 is mod-4-planed, waits are split per layer & batch-half:
//   lyr0 phase p: needs same-half lyr0 >= p+1 (h0 data), lyr1 >= p-1 (lagged anti-overwrite,
//                 2 phases of slack from the 4 h0 planes)
//   lyr1 phase p: needs same-half lyr0 >= p+1 (h0 data), lyr1 >= p+1 (h1 data + anti-overwrite)
// so the two layer-chains decouple: lyr1 stragglers no longer gate the lyr0 recurrence.
__global__ __launch_bounds__(256, 1) void lstm_coop(
    const int* __restrict__ x, const float* __restrict__ emb,
    const float* __restrict__ W0, const float* __restrict__ b0,
    const float* __restrict__ W1, const float* __restrict__ b1,
    const float* __restrict__ Wd, const float* __restrict__ bd,
    float* __restrict__ out, u16* __restrict__ ws) {

    const int tid  = threadIdx.x;
    const int lane = tid & 63;
    const int wave = tid >> 6;        // 0..3 : m-tile (16 rows each)
    const int quad = lane >> 4;       // 0..3 : k-chunk of 8 in frags
    const int fm   = lane & 15;       // A: m, B: n, C/D: col
    const int bid  = blockIdx.x;
    const int lyr  = bid & 1;
    const int inner= bid >> 1;
    const int bq   = inner >> 6;
    const int cg   = inner & 63;

    __shared__ u16   whi[128 * 32 * 8];   // 65,536 B (lyr0 uses first 104*32*8)
    __shared__ float csm[64 * 33];        //  8,448 B

    int* flags = (int*)ws;
    const u16* w0lo = ws + W0LOFF + (size_t)cg * 104 * 32 * 8;
    const u16* w1lo = ws + W1LOFF + (size_t)cg * 128 * 32 * 8;

    // --- fill LDS hi-plane (fp16), layout [kg][n][8] — R9 verbatim ---
    if (lyr == 0) {
        for (int i = tid; i < 104 * 32 * 8; i += 256) {
            int kg = i >> 8; int rem = i & 255; int n = rem >> 3; int j = rem & 7;
            int k = kg * 8 + j;
            int col = ((n >> 3) << 9) + (cg << 3) + (n & 7);
            float w = 0.f;
            if (k < 300) w = W0[k * 2048 + col];
            else if (k >= 320) w = W0[(k - 20) * 2048 + col];
            whi[i] = h_bits(w);
        }
    } else {
        for (int i = tid; i < 128 * 32 * 8; i += 256) {
            int kg = i >> 8; int rem = i & 255; int n = rem >> 3; int j = rem & 7;
            int k = kg * 8 + j;
            int col = ((n >> 3) << 9) + (cg << 3) + (n & 7);
            whi[i] = h_bits(W1[k * 2048 + col]);
        }
    }

    // --- zero-init own slice: lyr0 -> h0 plane 3 ((-1)&3, read by phase 0);
    //                          lyr1 -> h1 plane 1 (read by phase 1) ---
    {
        int row = bq * 64 + (tid >> 2);
        int c = (tid & 3) << 1;
        unsigned int* pz = (unsigned int*)(ws + (lyr ? H1OFF + 1 * HPAR : H0OFF + 3 * HPAR)
                                           + cg * 1024 + row * 8 + c);
        __hip_atomic_store(pz, 0u, __ATOMIC_RELAXED, __HIP_MEMORY_SCOPE_AGENT);
    }

    const int arow = bq * 64 + wave * 16 + fm;
    const int actm   = tid >> 2;
    const int acthc  = tid & 3;
    const int actrow = bq * 64 + actm;
    const int ca = (cg << 3) + acthc;
    const int cb = ca + 4;

    const float biA = lyr ? b1[ca]        : b0[ca];
    const float bjA = lyr ? b1[512 + ca]  : b0[512 + ca];
    const float bfA = lyr ? b1[1024 + ca] : b0[1024 + ca];
    const float boA = lyr ? b1[1536 + ca] : b0[1536 + ca];
    const float biB = lyr ? b1[cb]        : b0[cb];
    const float bjB = lyr ? b1[512 + cb]  : b0[512 + cb];
    const float bfB = lyr ? b1[1024 + cb] : b0[1024 + cb];
    const float boB = lyr ? b1[1536 + cb] : b0[1536 + cb];

    float csA = 0.f, csB = 0.f;

    // x-part GEMM of layer 0 for timestep pp (kt 0..9, both n-tiles) — R9 verbatim
    auto xgemm = [&](int pp) -> X4 {
        X4 a; a.h0 = (f4){0,0,0,0}; a.l0 = a.h0; a.h1 = a.h0; a.l1 = a.h0;
        int xi = x[arow * Tt + pp];
        xi = (xi < 0) ? 0 : ((xi >= 50000) ? 49999 : xi);
        const float* embrow = emb + (size_t)xi * 300;
#pragma unroll
        for (int kt = 0; kt < 10; kt++) {
            int kbase = kt * 32 + quad * 8;
            h8 af;
            if (kt < 9) {
                f4 u0 = *(const f4*)(embrow + kbase);
                f4 u1 = *(const f4*)(embrow + kbase + 4);
#pragma unroll
                for (int e = 0; e < 4; e++) { af[e] = (_Float16)u0[e]; af[4+e] = (_Float16)u1[e]; }
            } else {
#pragma unroll
                for (int e = 0; e < 8; e++) { int kk = kbase + e; af[e] = (_Float16)((kk < 300) ? embrow[kk] : 0.f); }
            }
            int kb = (kt * 4 + quad) * 32;
            a.h0 = MFMA(af, *(const h8*)&whi[(kb + fm) * 8],        a.h0, 0,0,0);
            a.l0 = MFMA(af, *(const h8*)(w0lo + (kb + fm) * 8),      a.l0, 0,0,0);
            a.h1 = MFMA(af, *(const h8*)&whi[(kb + 16 + fm) * 8],   a.h1, 0,0,0);
            a.l1 = MFMA(af, *(const h8*)(w0lo + (kb + 16 + fm) * 8), a.l1, 0,0,0);
        }
        return a;
    };

    X4 accx;
    barrier_arrive(flags, tid, bid, 1);
    if (lyr == 0) accx = xgemm(0);
    wait_split(flags, tid, bq, 1, 1);    // entering phase 0 (everyone has arrived 1)

    for (int p = 0; p <= Tt; ++p) {
        const int rp0 = (p + 3) & 3;     // h0 plane written at phase p-1 (read now)
        const int wp0 = p & 3;           // h0 plane this phase writes (lyr0)
        const int par = p & 1, wpar = 1 - par;   // h1 planes (mod-2, unchanged)

        if (lyr == 1) {
            if (p >= 1) {   // ---- layer 1 for t=p-1 : g1 = [h0(p-1) | h1(p-2)] @ W1 ----
                f4 aH0 = (f4){0,0,0,0}, aL0 = aH0, aH1 = aH0, aL1 = aH0;
                const u16* h0p = ws + H0OFF + rp0 * HPAR + arow * 8;
                const u16* h1p = ws + H1OFF + par * HPAR + arow * 8;
#pragma unroll 8
                for (int kt = 0; kt < 32; kt++) {
                    h8 af = (kt < 16) ? ldH(h0p + (kt * 4 + quad) * 1024)
                                      : ldH(h1p + ((kt - 16) * 4 + quad) * 1024);
                    int kb = (kt * 4 + quad) * 32;
                    aH0 = MFMA(af, *(const h8*)&whi[(kb + fm) * 8],        aH0, 0,0,0);
                    aL0 = MFMA(af, *(const h8*)(w1lo + (kb + fm) * 8),      aL0, 0,0,0);
                    aH1 = MFMA(af, *(const h8*)&whi[(kb + 16 + fm) * 8],   aH1, 0,0,0);
                    aL1 = MFMA(af, *(const h8*)(w1lo + (kb + 16 + fm) * 8), aL1, 0,0,0);
                }
#pragma unroll
                for (int r = 0; r < 4; r++) {
                    csm[(wave * 16 + quad * 4 + r) * 33 + fm]      = aH0[r] + aL0[r] * LOSC;
                    csm[(wave * 16 + quad * 4 + r) * 33 + 16 + fm] = aH1[r] + aL1[r] * LOSC;
                }
                __syncthreads();
                {
                    float giA = csm[actm * 33 + acthc]      + biA;
                    float gjA = csm[actm * 33 + 8 + acthc]  + bjA;
                    float gfA = csm[actm * 33 + 16 + acthc] + bfA;
                    float goA = csm[actm * 33 + 24 + acthc] + boA;
                    float giB = csm[actm * 33 + 4 + acthc]  + biB;
                    float gjB = csm[actm * 33 + 12 + acthc] + bjB;
                    float gfB = csm[actm * 33 + 20 + acthc] + bfB;
                    float goB = csm[actm * 33 + 28 + acthc] + boB;
                    csA = csA * sigm(gfA + 1.f) + sigm(giA) * tanhf(gjA);
                    csB = csB * sigm(gfB + 1.f) + sigm(giB) * tanhf(gjB);
                    float hA = tanhf(csA) * sigm(goA);
                    float hB = tanhf(csB) * sigm(goB);
                    u16 ha = h_bits(hA), hb = h_bits(hB);
                    unsigned int pa = (unsigned int)ha | (((unsigned int)(u16)__shfl_xor((int)ha, 1, 64)) << 16);
                    unsigned int pb = (unsigned int)hb | (((unsigned int)(u16)__shfl_xor((int)hb, 1, 64)) << 16);
                    if (!(acthc & 1)) {
                        u16* base = ws + H1OFF + wpar * HPAR + cg * 1024 + actrow * 8;
                        __hip_atomic_store((unsigned int*)(base + acthc),     pa, __ATOMIC_RELAXED, __HIP_MEMORY_SCOPE_AGENT);
                        __hip_atomic_store((unsigned int*)(base + 4 + acthc), pb, __ATOMIC_RELAXED, __HIP_MEMORY_SCOPE_AGENT);
                    }
                }
            }
        } else {
            if (p < Tt) {   // ---- layer 0 h-part for t=p (x-part already in accx) ----
                f4 aH0 = accx.h0, aL0 = accx.l0, aH1 = accx.h1, aL1 = accx.l1;
                const u16* h0p = ws + H0OFF + rp0 * HPAR + arow * 8;
#pragma unroll 8
                for (int kt = 10; kt < 26; kt++) {
                    h8 af = ldH(h0p + (kt * 4 + quad - 40) * 1024);
                    int kb = (kt * 4 + quad) * 32;
                    aH0 = MFMA(af, *(const h8*)&whi[(kb + fm) * 8],        aH0, 0,0,0);
                    aL0 = MFMA(af, *(const h8*)(w0lo + (kb + fm) * 8),      aL0, 0,0,0);
                    aH1 = MFMA(af, *(const h8*)&whi[(kb + 16 + fm) * 8],   aH1, 0,0,0);
                    aL1 = MFMA(af, *(const h8*)(w0lo + (kb + 16 + fm) * 8), aL1, 0,0,0);
                }
#pragma unroll
                for (int r = 0; r < 4; r++) {
                    csm[(wave * 16 + quad * 4 + r) * 33 + fm]      = aH0[r] + aL0[r] * LOSC;
                    csm[(wave * 16 + quad * 4 + r) * 33 + 16 + fm] = aH1[r] + aL1[r] * LOSC;
                }
                __syncthreads();
                {
                    float giA = csm[actm * 33 + acthc]      + biA;
                    float gjA = csm[actm * 33 + 8 + acthc]  + bjA;
                    float gfA = csm[actm * 33 + 16 + acthc] + bfA;
                    float goA = csm[actm * 33 + 24 + acthc] + boA;
                    float giB = csm[actm * 33 + 4 + acthc]  + biB;
                    float gjB = csm[actm * 33 + 12 + acthc] + bjB;
                    float gfB = csm[actm * 33 + 20 + acthc] + bfB;
                    float goB = csm[actm * 33 + 28 + acthc] + boB;
                    csA = csA * sigm(gfA + 1.f) + sigm(giA) * tanhf(gjA);
                    csB = csB * sigm(gfB + 1.f) + sigm(giB) * tanhf(gjB);
                    float hA = tanhf(csA) * sigm(goA);
                    float hB = tanhf(csB) * sigm(goB);
                    u16 ha = h_bits(hA), hb = h_bits(hB);
                    unsigned int pa = (unsigned int)ha | (((unsigned int)(u16)__shfl_xor((int)ha, 1, 64)) << 16);
                    unsigned int pb = (unsigned int)hb | (((unsigned int)(u16)__shfl_xor((int)hb, 1, 64)) << 16);
                    if (!(acthc & 1)) {
                        u16* base = ws + H0OFF + wp0 * HPAR + cg * 1024 + actrow * 8;
                        __hip_atomic_store((unsigned int*)(base + acthc),     pa, __ATOMIC_RELAXED, __HIP_MEMORY_SCOPE_AGENT);
                        __hip_atomic_store((unsigned int*)(base + 4 + acthc), pb, __ATOMIC_RELAXED, __HIP_MEMORY_SCOPE_AGENT);
                    }
                }
            }
        }

        barrier_arrive(flags, tid, bid, p + 2);
        if (lyr == 0 && p + 1 < Tt) accx = xgemm(p + 1);
        // entering phase p+1:
        //   lyr0: lyr0-half >= p+2 (h0 data), lyr1-half >= p (lagged anti-overwrite)
        //   lyr1: both halves' layers >= p+2 (h1 data + h0 data + anti-overwrite)
        if (lyr == 0) wait_split(flags, tid, bq, p + 2, p);
        else          wait_split(flags, tid, bq, p + 2, p + 2);
    }

    // ---- final logits: wait for ALL 256 blocks (both halves) >= Tt+2, then read h1(T-1)
    //      (plane 1: phase Tt has parity 0, writes wpar=1) ----
    if (bid == 0) {
        if (tid < 64) {
            for (;;) {
                ull a = __hip_atomic_load((const ull*)(flags + (tid << 1)),       __ATOMIC_RELAXED, __HIP_MEMORY_SCOPE_AGENT);
                ull b = __hip_atomic_load((const ull*)(flags + 128 + (tid << 1)), __ATOMIC_RELAXED, __HIP_MEMORY_SCOPE_AGENT);
                bool ok = ((int)(unsigned)a >= Tt + 2) && ((int)(unsigned)(a >> 32) >= Tt + 2) &&
                          ((int)(unsigned)b >= Tt + 2) && ((int)(unsigned)(b >> 32) >= Tt + 2);
                if (__ballot(ok) == ~0ull) break;
                __builtin_amdgcn_s_sleep(1);
            }
        }
        __syncthreads();
        int b = tid >> 1, jj = tid & 1;
        float sum = bd[jj];
        const u16* hh = ws + H1OFF + 1 * HPAR;
        for (int g = 0; g < 64; g++) {
#pragma unroll
            for (int j4 = 0; j4 < 8; j4 += 4) {
                ull u = __hip_atomic_load((const ull*)(hh + (g * 128 + b) * 8 + j4),
                                          __ATOMIC_RELAXED, __HIP_MEMORY_SCOPE_AGENT);
#pragma unroll
                for (int e = 0; e < 4; e++)
                    sum += bits_f((u16)(u >> (16 * e))) * Wd[(g * 8 + j4 + e) * 2 + jj];
            }
        }
        out[b * 2 + jj] = sum;
    }
}

extern "C" void kernel_launch(void* const* d_in, const int* in_sizes, int n_in,
                              void* d_out, int out_size, void* d_ws, size_t ws_size,
                              hipStream_t stream) {
    const int*   x   = (const int*)d_in[0];
    const float* emb = (const float*)d_in[1];
    const float* W0  = (const float*)d_in[2];
    const float* b0  = (const float*)d_in[3];
    const float* W1  = (const float*)d_in[4];
    const float* b1  = (const float*)d_in[5];
    const float* Wd  = (const float*)d_in[6];
    const float* bd  = (const float*)d_in[7];
    float* out = (float*)d_out;
    u16* ws = (u16*)d_ws;

    hipLaunchKernelGGL(prepack, dim3(1856), dim3(256), 0, stream, W0, W1, ws);

    void* args[] = { (void*)&x, (void*)&emb, (void*)&W0, (void*)&b0, (void*)&W1,
                     (void*)&b1, (void*)&Wd, (void*)&bd, (void*)&out, (void*)&ws };
    hipLaunchCooperativeKernel((void*)lstm_coop, dim3(256), dim3(256), args, 0, stream);
}

// Round 14
// 4238.020 us; speedup vs baseline: 1.0217x; 1.0217x over previous
//
#include <hip/hip_runtime.h>

// Problem constants
#define Tt 256

// ws layout in unsigned shorts (fp16 bit patterns / ints for flags):
//  flags : ints [0..256) arrival flags (4B packed)      [first 1KB of 32KB region]
//  h0 [2 parity][64 g][2 half][128 row][4]  fp16        [256 KB]
//     (g = col>>3, half = (col>>2)&1 — R14: half-split so each 8B packed store
//      instruction covers full cachelines -> MALL write-allocate, IF$-served reads)
//  h1 same                                              [256 KB]
//  w0lo [64 cg][104 kg][32 n][8]  fp16, lo=(w-fp16(w))*1024, block-private frag-lane order
//  w1lo [64 cg][128 kg][32 n][8]
// total = 4,079,616 shorts = 8,159,232 B (byte-identical to the R5..R11 proven budget)
#define FLAGS_SHORTS 16384
#define H0OFF  16384
#define H1OFF  (H0OFF + 2*64*128*8)
#define W0LOFF (H1OFF + 2*64*128*8)
#define W1LOFF (W0LOFF + 64*104*32*8)
#define HPAR   (64*128*8)            // u16 per parity plane = 65536 (unchanged size)

typedef _Float16 h8 __attribute__((ext_vector_type(8)));
typedef float    f4 __attribute__((ext_vector_type(4)));
typedef unsigned long long ull;
typedef unsigned short u16;

#define MFMA __builtin_amdgcn_mfma_f32_16x16x32_f16
#define LOSC (1.0f/1024.0f)

__device__ inline u16 h_bits(float f){ union{_Float16 h; u16 s;} u; u.h=(_Float16)f; return u.s; }
__device__ inline float bits_f(u16 s){ union{u16 s2; _Float16 h;} u; u.s2=s; return (float)u.h; }
__device__ inline float sigm(float x){ return 1.f/(1.f+expf(-x)); }

// Coherent A-fragment load from half-split layout: two relaxed agent-scope 8B atomic
// loads (IF$ path, proven R2..R13). p points at [g][0][row][0]; +512 u16 = hi half.
// Element order preserved: u[0] = cols 0-3, u[1] = cols 4-7.
__device__ inline h8 ldH(const u16* p){
    union{ ull u[2]; h8 v; } t;
    t.u[0]=__hip_atomic_load((const ull*)p,        __ATOMIC_RELAXED, __HIP_MEMORY_SCOPE_AGENT);
    t.u[1]=__hip_atomic_load((const ull*)(p + 512),__ATOMIC_RELAXED, __HIP_MEMORY_SCOPE_AGENT);
    return t.v;
}

// ---------------- pre-pack W lo-planes (fp16, x1024), [cg][kg][n 0..32)[8] — R9 verbatim ----------------
__global__ __launch_bounds__(256) void prepack(const float* __restrict__ W0,
                                               const float* __restrict__ W1,
                                               u16* __restrict__ ws) {
    int idx = blockIdx.x * 256 + threadIdx.x;
    const int NW0 = 64 * 104 * 32;
    if (idx < NW0) {
        int cg  = idx / (104 * 32);
        int rem = idx - cg * (104 * 32);
        int kg = rem >> 5, n = rem & 31;
        int col = ((n >> 3) << 9) + (cg << 3) + (n & 7);
        u16 t[8];
#pragma unroll
        for (int j = 0; j < 8; j++) {
            int k = kg * 8 + j;
            float w = 0.f;
            if (k < 300) w = W0[k * 2048 + col];
            else if (k >= 320) w = W0[(k - 20) * 2048 + col];
            _Float16 wh = (_Float16)w;
            t[j] = h_bits((w - (float)wh) * 1024.0f);
        }
#pragma unroll
        for (int j = 0; j < 8; j++) ws[W0LOFF + (size_t)idx * 8 + j] = t[j];
    } else {
        int i2 = idx - NW0;
        if (i2 < 64 * 128 * 32) {
            int cg  = i2 >> 12;
            int rem = i2 & 4095;
            int kg = rem >> 5, n = rem & 31;
            int col = ((n >> 3) << 9) + (cg << 3) + (n & 7);
            u16 t[8];
#pragma unroll
            for (int j = 0; j < 8; j++) {
                float w = W1[(kg * 8 + j) * 2048 + col];
                _Float16 wh = (_Float16)w;
                t[j] = h_bits((w - (float)wh) * 1024.0f);
            }
#pragma unroll
            for (int j = 0; j < 8; j++) ws[W1LOFF + (size_t)i2 * 8 + j] = t[j];
        }
    }
}

// Fence-free split barrier — R11 verbatim (proven): arrive publishes own flag after
// write-drain; only wave 0 polls all 256 flags via two coalesced 8B/lane loads.
__device__ inline void barrier_arrive(int* __restrict__ flags, int tid, int bid, int target) {
    __builtin_amdgcn_s_waitcnt(0);
    __syncthreads();
    if (tid == 0)
        __hip_atomic_store(flags + bid, target, __ATOMIC_RELAXED, __HIP_MEMORY_SCOPE_AGENT);
}
__device__ inline void barrier_wait(int* __restrict__ flags, int tid, int target) {
    if (tid < 64) {
        for (;;) {
            ull a = __hip_atomic_load((const ull*)(flags + (tid << 1)),       __ATOMIC_RELAXED, __HIP_MEMORY_SCOPE_AGENT);
            ull b = __hip_atomic_load((const ull*)(flags + 128 + (tid << 1)), __ATOMIC_RELAXED, __HIP_MEMORY_SCOPE_AGENT);
            bool ok = ((int)(unsigned)a >= target) && ((int)(unsigned)(a >> 32) >= target) &&
                      ((int)(unsigned)b >= target) && ((int)(unsigned)(b >> 32) >= target);
            if (__ballot(ok) == ~0ull) break;
            __builtin_amdgcn_s_sleep(1);
        }
    }
    __syncthreads();
}

struct X4 { f4 h0, l0, h1, l1; };

// ---------------- persistent cooperative LSTM kernel ----------------
// grid 256 x 256 (1 block/CU): bid = inner*2 + lyr; inner = bq*64 + cg.
// R11 structure verbatim. R14 change: h planes use [g][half][row][4] layout and the
// act epilogue shfl-packs 4 lanes' u16s into one 8B dense atomic store (full-line
// coverage per store instruction -> MALL write-allocate -> consumer loads IF$-hit).
__global__ __launch_bounds__(256, 1) void lstm_coop(
    const int* __restrict__ x, const float* __restrict__ emb,
    const float* __restrict__ W0, const float* __restrict__ b0,
    const float* __restrict__ W1, const float* __restrict__ b1,
    const float* __restrict__ Wd, const float* __restrict__ bd,
    float* __restrict__ out, u16* __restrict__ ws) {

    const int tid  = threadIdx.x;
    const int lane = tid & 63;
    const int wave = tid >> 6;        // 0..3 : m-tile (16 rows each)
    const int quad = lane >> 4;       // 0..3 : k-chunk of 8 in frags
    const int fm   = lane & 15;       // A: m, B: n, C/D: col
    const int bid  = blockIdx.x;
    const int lyr  = bid & 1;
    const int inner= bid >> 1;
    const int bq   = inner >> 6;
    const int cg   = inner & 63;

    __shared__ u16   whi[128 * 32 * 8];   // 65,536 B (lyr0 uses first 104*32*8)
    __shared__ float csm[64 * 33];        //  8,448 B

    int* flags = (int*)ws;
    const u16* w0lo = ws + W0LOFF + (size_t)cg * 104 * 32 * 8;
    const u16* w1lo = ws + W1LOFF + (size_t)cg * 128 * 32 * 8;

    // --- fill LDS hi-plane (fp16), layout [kg][n][8] — R9 verbatim ---
    if (lyr == 0) {
        for (int i = tid; i < 104 * 32 * 8; i += 256) {
            int kg = i >> 8; int rem = i & 255; int n = rem >> 3; int j = rem & 7;
            int k = kg * 8 + j;
            int col = ((n >> 3) << 9) + (cg << 3) + (n & 7);
            float w = 0.f;
            if (k < 300) w = W0[k * 2048 + col];
            else if (k >= 320) w = W0[(k - 20) * 2048 + col];
            whi[i] = h_bits(w);
        }
    } else {
        for (int i = tid; i < 128 * 32 * 8; i += 256) {
            int kg = i >> 8; int rem = i & 255; int n = rem >> 3; int j = rem & 7;
            int k = kg * 8 + j;
            int col = ((n >> 3) << 9) + (cg << 3) + (n & 7);
            whi[i] = h_bits(W1[k * 2048 + col]);
        }
    }

    // --- zero-init own slice (dense 8B stores): lyr0 -> h0 parity 0 ; lyr1 -> h1 parity 1 ---
    if (tid < 128) {
        int row  = bq * 64 + (tid & 63);
        int half = tid >> 6;
        ull* pz = (ull*)(ws + (lyr ? H1OFF + 1 * HPAR : H0OFF + 0 * HPAR)
                         + cg * 1024 + half * 512 + row * 4);
        __hip_atomic_store(pz, 0ull, __ATOMIC_RELAXED, __HIP_MEMORY_SCOPE_AGENT);
    }

    const int arow = bq * 64 + wave * 16 + fm;
    const int actm   = tid >> 2;
    const int acthc  = tid & 3;
    const int actrow = bq * 64 + actm;
    const int ca = (cg << 3) + acthc;
    const int cb = ca + 4;

    const float biA = lyr ? b1[ca]        : b0[ca];
    const float bjA = lyr ? b1[512 + ca]  : b0[512 + ca];
    const float bfA = lyr ? b1[1024 + ca] : b0[1024 + ca];
    const float boA = lyr ? b1[1536 + ca] : b0[1536 + ca];
    const float biB = lyr ? b1[cb]        : b0[cb];
    const float bjB = lyr ? b1[512 + cb]  : b0[512 + cb];
    const float bfB = lyr ? b1[1024 + cb] : b0[1024 + cb];
    const float boB = lyr ? b1[1536 + cb] : b0[1536 + cb];

    float csA = 0.f, csB = 0.f;

    // packed dense h-store: 4 consecutive lanes (acthc 0..3, same row) shfl-gather
    // their cols; lane acthc==0 stores cols 0-3 (lo half), acthc==1 stores cols 4-7.
    auto storeH = [&](u16* planeBase, float hA, float hB) {
        u16 ha = h_bits(hA), hb = h_bits(hB);
        int gb = lane & ~3;
        ull pkA = 0, pkB = 0;
#pragma unroll
        for (int j = 0; j < 4; j++) {
            pkA |= (ull)(u16)__shfl((int)ha, gb + j, 64) << (16 * j);
            pkB |= (ull)(u16)__shfl((int)hb, gb + j, 64) << (16 * j);
        }
        u16* rowp = planeBase + cg * 1024 + actrow * 4;
        if (acthc == 0)
            __hip_atomic_store((ull*)rowp,         pkA, __ATOMIC_RELAXED, __HIP_MEMORY_SCOPE_AGENT);
        else if (acthc == 1)
            __hip_atomic_store((ull*)(rowp + 512), pkB, __ATOMIC_RELAXED, __HIP_MEMORY_SCOPE_AGENT);
    };

    // x-part GEMM of layer 0 for timestep pp (kt 0..9, both n-tiles) — R9 verbatim
    auto xgemm = [&](int pp) -> X4 {
        X4 a; a.h0 = (f4){0,0,0,0}; a.l0 = a.h0; a.h1 = a.h0; a.l1 = a.h0;
        int xi = x[arow * Tt + pp];
        xi = (xi < 0) ? 0 : ((xi >= 50000) ? 49999 : xi);
        const float* embrow = emb + (size_t)xi * 300;
#pragma unroll
        for (int kt = 0; kt < 10; kt++) {
            int kbase = kt * 32 + quad * 8;
            h8 af;
            if (kt < 9) {
                f4 u0 = *(const f4*)(embrow + kbase);
                f4 u1 = *(const f4*)(embrow + kbase + 4);
#pragma unroll
                for (int e = 0; e < 4; e++) { af[e] = (_Float16)u0[e]; af[4+e] = (_Float16)u1[e]; }
            } else {
#pragma unroll
                for (int e = 0; e < 8; e++) { int kk = kbase + e; af[e] = (_Float16)((kk < 300) ? embrow[kk] : 0.f); }
            }
            int kb = (kt * 4 + quad) * 32;
            a.h0 = MFMA(af, *(const h8*)&whi[(kb + fm) * 8],        a.h0, 0,0,0);
            a.l0 = MFMA(af, *(const h8*)(w0lo + (kb + fm) * 8),      a.l0, 0,0,0);
            a.h1 = MFMA(af, *(const h8*)&whi[(kb + 16 + fm) * 8],   a.h1, 0,0,0);
            a.l1 = MFMA(af, *(const h8*)(w0lo + (kb + 16 + fm) * 8), a.l1, 0,0,0);
        }
        return a;
    };

    X4 accx;
    barrier_arrive(flags, tid, bid, 1);
    if (lyr == 0) accx = xgemm(0);
    barrier_wait(flags, tid, 1);

    for (int p = 0; p <= Tt; ++p) {
        const int par = p & 1, wpar = 1 - par;

        if (lyr == 1) {
            if (p >= 1) {   // ---- layer 1 for t=p-1 : g1 = [h0(p-1) | h1(p-2)] @ W1 ----
                f4 aH0 = (f4){0,0,0,0}, aL0 = aH0, aH1 = aH0, aL1 = aH0;
                const u16* h0p = ws + H0OFF + par * HPAR + arow * 4;
                const u16* h1p = ws + H1OFF + par * HPAR + arow * 4;
#pragma unroll 8
                for (int kt = 0; kt < 32; kt++) {
                    h8 af = (kt < 16) ? ldH(h0p + (kt * 4 + quad) * 1024)
                                      : ldH(h1p + ((kt - 16) * 4 + quad) * 1024);
                    int kb = (kt * 4 + quad) * 32;
                    aH0 = MFMA(af, *(const h8*)&whi[(kb + fm) * 8],        aH0, 0,0,0);
                    aL0 = MFMA(af, *(const h8*)(w1lo + (kb + fm) * 8),      aL0, 0,0,0);
                    aH1 = MFMA(af, *(const h8*)&whi[(kb + 16 + fm) * 8],   aH1, 0,0,0);
                    aL1 = MFMA(af, *(const h8*)(w1lo + (kb + 16 + fm) * 8), aL1, 0,0,0);
                }
#pragma unroll
                for (int r = 0; r < 4; r++) {
                    csm[(wave * 16 + quad * 4 + r) * 33 + fm]      = aH0[r] + aL0[r] * LOSC;
                    csm[(wave * 16 + quad * 4 + r) * 33 + 16 + fm] = aH1[r] + aL1[r] * LOSC;
                }
                __syncthreads();
                {
                    float giA = csm[actm * 33 + acthc]      + biA;
                    float gjA = csm[actm * 33 + 8 + acthc]  + bjA;
                    float gfA = csm[actm * 33 + 16 + acthc] + bfA;
                    float goA = csm[actm * 33 + 24 + acthc] + boA;
                    float giB = csm[actm * 33 + 4 + acthc]  + biB;
                    float gjB = csm[actm * 33 + 12 + acthc] + bjB;
                    float gfB = csm[actm * 33 + 20 + acthc] + bfB;
                    float goB = csm[actm * 33 + 28 + acthc] + boB;
                    csA = csA * sigm(gfA + 1.f) + sigm(giA) * tanhf(gjA);
                    csB = csB * sigm(gfB + 1.f) + sigm(giB) * tanhf(gjB);
                    storeH(ws + H1OFF + wpar * HPAR, tanhf(csA) * sigm(goA), tanhf(csB) * sigm(goB));
                }
            }
        } else {
            if (p < Tt) {   // ---- layer 0 h-part for t=p (x-part already in accx) ----
                f4 aH0 = accx.h0, aL0 = accx.l0, aH1 = accx.h1, aL1 = accx.l1;
                const u16* h0p = ws + H0OFF + par * HPAR + arow * 4;
#pragma unroll 8
                for (int kt = 10; kt < 26; kt++) {
                    h8 af = ldH(h0p + (kt * 4 + quad - 40) * 1024);
                    int kb = (kt * 4 + quad) * 32;
                    aH0 = MFMA(af, *(const h8*)&whi[(kb + fm) * 8],        aH0, 0,0,0);
                    aL0 = MFMA(af, *(const h8*)(w0lo + (kb + fm) * 8),      aL0, 0,0,0);
                    aH1 = MFMA(af, *(const h8*)&whi[(kb + 16 + fm) * 8],   aH1, 0,0,0);
                    aL1 = MFMA(af, *(const h8*)(w0lo + (kb + 16 + fm) * 8), aL1, 0,0,0);
                }
#pragma unroll
                for (int r = 0; r < 4; r++) {
                    csm[(wave * 16 + quad * 4 + r) * 33 + fm]      = aH0[r] + aL0[r] * LOSC;
                    csm[(wave * 16 + quad * 4 + r) * 33 + 16 + fm] = aH1[r] + aL1[r] * LOSC;
                }
                __syncthreads();
                {
                    float giA = csm[actm * 33 + acthc]      + biA;
                    float gjA = csm[actm * 33 + 8 + acthc]  + bjA;
                    float gfA = csm[actm * 33 + 16 + acthc] + bfA;
                    float goA = csm[actm * 33 + 24 + acthc] + boA;
                    float giB = csm[actm * 33 + 4 + acthc]  + biB;
                    float gjB = csm[actm * 33 + 12 + acthc] + bjB;
                    float gfB = csm[actm * 33 + 20 + acthc] + bfB;
                    float goB = csm[actm * 33 + 28 + acthc] + boB;
                    csA = csA * sigm(gfA + 1.f) + sigm(giA) * tanhf(gjA);
                    csB = csB * sigm(gfB + 1.f) + sigm(giB) * tanhf(gjB);
                    storeH(ws + H0OFF + wpar * HPAR, tanhf(csA) * sigm(goA), tanhf(csB) * sigm(goB));
                }
            }
        }

        barrier_arrive(flags, tid, bid, p + 2);
        if (lyr == 0 && p + 1 < Tt) accx = xgemm(p + 1);
        barrier_wait(flags, tid, p + 2);
    }

    // ---- final logits: h1(T-1) lives in parity 1 (half-split addressing) ----
    if (bid == 0) {
        int b = tid >> 1, jj = tid & 1;
        float sum = bd[jj];
        const u16* hh = ws + H1OFF + 1 * HPAR;
        for (int g = 0; g < 64; g++) {
            ull uA = __hip_atomic_load((const ull*)(hh + g * 1024 + b * 4),
                                       __ATOMIC_RELAXED, __HIP_MEMORY_SCOPE_AGENT);
            ull uB = __hip_atomic_load((const ull*)(hh + g * 1024 + 512 + b * 4),
                                       __ATOMIC_RELAXED, __HIP_MEMORY_SCOPE_AGENT);
#pragma unroll
            for (int e = 0; e < 4; e++) {
                sum += bits_f((u16)(uA >> (16 * e))) * Wd[(g * 8 + e) * 2 + jj];
                sum += bits_f((u16)(uB >> (16 * e))) * Wd[(g * 8 + 4 + e) * 2 + jj];
            }
        }
        out[b * 2 + jj] = sum;
    }
}

extern "C" void kernel_launch(void* const* d_in, const int* in_sizes, int n_in,
                              void* d_out, int out_size, void* d_ws, size_t ws_size,
                              hipStream_t stream) {
    const int*   x   = (const int*)d_in[0];
    const float* emb = (const float*)d_in[1];
    const float* W0  = (const float*)d_in[2];
    const float* b0  = (const float*)d_in[3];
    const float* W1  = (const float*)d_in[4];
    const float* b1  = (const float*)d_in[5];
    const float* Wd  = (const float*)d_in[6];
    const float* bd  = (const float*)d_in[7];
    float* out = (float*)d_out;
    u16* ws = (u16*)d_ws;

    hipLaunchKernelGGL(prepack, dim3(1856), dim3(256), 0, stream, W0, W1, ws);

    void* args[] = { (void*)&x, (void*)&emb, (void*)&W0, (void*)&b0, (void*)&W1,
                     (void*)&b1, (void*)&Wd, (void*)&bd, (void*)&out, (void*)&ws };
    hipLaunchCooperativeKernel((void*)lstm_coop, dim3(256), dim3(256), args, 0, stream);
}